// Round 1
// baseline (391.360 us; speedup 1.0000x reference)
//
#include <hip/hip_runtime.h>
#include <cstdint>
#include <cstddef>

typedef __bf16 bf16x8 __attribute__((ext_vector_type(8)));
typedef float f32x4 __attribute__((ext_vector_type(4)));
typedef unsigned short ushort8 __attribute__((ext_vector_type(8)));
typedef float f4 __attribute__((ext_vector_type(4)));

__device__ __forceinline__ unsigned short f2bf(float f) {
    union { float f; unsigned int u; } v; v.f = f;
    unsigned int u = v.u;
    unsigned int r = u + 0x7FFFu + ((u >> 16) & 1u);   // round-to-nearest-even
    return (unsigned short)(r >> 16);
}

// ---------------------------------------------------------------------------
// 1. Convert the four 512x512 fp32 weight matrices to bf16 (concatenated).
// ---------------------------------------------------------------------------
__global__ __launch_bounds__(256) void convert_w(
    const float* __restrict__ wq, const float* __restrict__ wk,
    const float* __restrict__ wv, const float* __restrict__ wo,
    unsigned short* __restrict__ out)
{
    int i = blockIdx.x * 256 + threadIdx.x;   // grid 4096 -> 1048576 elements
    const float* src = (i < 262144) ? wq : (i < 524288) ? wk : (i < 786432) ? wv : wo;
    out[i] = f2bf(src[i & 262143]);
}

// ---------------------------------------------------------------------------
// 2. GroupNorm: one block per (batch, group). Group = 16 channels x 4096 spatial
//    = contiguous 64K floats. Writes h as bf16 in [B*N, C] layout (transposed).
// ---------------------------------------------------------------------------
__global__ __launch_bounds__(256) void groupnorm_kernel(
    const float* __restrict__ x, const float* __restrict__ gamma,
    const float* __restrict__ beta, unsigned short* __restrict__ h)
{
    const int bid = blockIdx.x;           // 64 = 2 batches * 32 groups
    const int b = bid >> 5, g = bid & 31;
    const float* xg = x + ((size_t)(b * 512 + g * 16)) * 4096;
    const int t = threadIdx.x;

    float s = 0.f, sq = 0.f;
    const f4* xv = (const f4*)xg;         // 16384 float4
    for (int i = t; i < 16384; i += 256) {
        f4 v = xv[i];
        s  += v.x + v.y + v.z + v.w;
        sq += v.x * v.x + v.y * v.y + v.z * v.z + v.w * v.w;
    }
    #pragma unroll
    for (int off = 32; off > 0; off >>= 1) {
        s  += __shfl_xor(s, off, 64);
        sq += __shfl_xor(sq, off, 64);
    }
    __shared__ float red[8];
    __shared__ float stats[2];
    const int w = t >> 6, lane = t & 63;
    if (lane == 0) { red[w] = s; red[4 + w] = sq; }
    __syncthreads();
    if (t == 0) {
        float ts = red[0] + red[1] + red[2] + red[3];
        float tq = red[4] + red[5] + red[6] + red[7];
        float mean = ts * (1.f / 65536.f);
        float var  = tq * (1.f / 65536.f) - mean * mean;
        stats[0] = mean;
        stats[1] = rsqrtf(var + 1e-5f);
    }
    __syncthreads();
    const float mean = stats[0], rstd = stats[1];
    float gm[16], bt[16];
    #pragma unroll
    for (int c = 0; c < 16; ++c) {
        gm[c] = gamma[g * 16 + c] * rstd;
        bt[c] = beta[g * 16 + c];
    }
    // pass 2: each thread owns one spatial column -> 16 contiguous bf16 out
    for (int nt = 0; nt < 16; ++nt) {
        const int n = nt * 256 + t;
        ushort8 v0, v1;
        #pragma unroll
        for (int c = 0; c < 8; ++c) {
            float v = xg[(size_t)c * 4096 + n];
            v0[c] = f2bf((v - mean) * gm[c] + bt[c]);
        }
        #pragma unroll
        for (int c = 8; c < 16; ++c) {
            float v = xg[(size_t)c * 4096 + n];
            v1[c - 8] = f2bf((v - mean) * gm[c] + bt[c]);
        }
        unsigned short* dst = h + ((size_t)(b * 4096 + n)) * 512 + g * 16;
        *(ushort8*)dst = v0;
        *(ushort8*)(dst + 8) = v1;
    }
}

// ---------------------------------------------------------------------------
// 3. bf16 GEMM  C[i,j] = sum_k A[i,k]*Bt[j,k] (+bias, +epilogue)
//    MODE 0: out bf16 at [i*N + j], bias indexed by j   (QKV projections)
//    MODE 1: out fp32 transposed to [B,C,H,W] with residual, bias by i (final)
//    128x128 tile, BK=32, 4 waves of 64x64, 16x16x32 MFMA.
// ---------------------------------------------------------------------------
template <int MODE>
__global__ __launch_bounds__(256, 2) void gemm_bt(
    const unsigned short* __restrict__ A,   // [M,K] bf16
    const unsigned short* __restrict__ Bt,  // [N,K] bf16
    const float* __restrict__ bias,
    const float* __restrict__ resid,        // x for MODE 1
    void* __restrict__ outp,
    int M, int N, int K)
{
    __shared__ __attribute__((aligned(16))) unsigned short As[128 * 32];
    __shared__ __attribute__((aligned(16))) unsigned short Bs[128 * 32];
    const int t = threadIdx.x;
    const int w = t >> 6, lane = t & 63;
    const int l15 = lane & 15, l4 = lane >> 4;
    const int bm = blockIdx.y, bn = blockIdx.x;
    const int wm = (w >> 1) * 64, wn = (w & 1) * 64;

    f32x4 acc[4][4] = {};

    const int srow = t >> 2;            // 0..63
    const int sc8  = (t & 3) * 8;       // 0,8,16,24

    for (int k0 = 0; k0 < K; k0 += 32) {
        __syncthreads();
        ushort8 va0 = *(const ushort8*)(A  + (size_t)(bm * 128 + srow) * K + k0 + sc8);
        ushort8 va1 = *(const ushort8*)(A  + (size_t)(bm * 128 + 64 + srow) * K + k0 + sc8);
        ushort8 vb0 = *(const ushort8*)(Bt + (size_t)(bn * 128 + srow) * K + k0 + sc8);
        ushort8 vb1 = *(const ushort8*)(Bt + (size_t)(bn * 128 + 64 + srow) * K + k0 + sc8);
        *(ushort8*)&As[t * 8]        = va0;
        *(ushort8*)&As[t * 8 + 2048] = va1;
        *(ushort8*)&Bs[t * 8]        = vb0;
        *(ushort8*)&Bs[t * 8 + 2048] = vb1;
        __syncthreads();

        bf16x8 af[4], bfr[4];
        #pragma unroll
        for (int mt = 0; mt < 4; ++mt)
            af[mt] = *(const bf16x8*)&As[(wm + mt * 16 + l15) * 32 + l4 * 8];
        #pragma unroll
        for (int nt = 0; nt < 4; ++nt)
            bfr[nt] = *(const bf16x8*)&Bs[(wn + nt * 16 + l15) * 32 + l4 * 8];
        #pragma unroll
        for (int mt = 0; mt < 4; ++mt)
            #pragma unroll
            for (int nt = 0; nt < 4; ++nt)
                acc[mt][nt] = __builtin_amdgcn_mfma_f32_16x16x32_bf16(
                    af[mt], bfr[nt], acc[mt][nt], 0, 0, 0);
    }

    if (MODE == 0) {
        unsigned short* outB = (unsigned short*)outp;
        #pragma unroll
        for (int mt = 0; mt < 4; ++mt)
            #pragma unroll
            for (int nt = 0; nt < 4; ++nt)
                #pragma unroll
                for (int r = 0; r < 4; ++r) {
                    int row = bm * 128 + wm + mt * 16 + l4 * 4 + r;
                    int col = bn * 128 + wn + nt * 16 + l15;
                    outB[(size_t)row * N + col] = f2bf(acc[mt][nt][r] + bias[col]);
                }
    } else {
        float* outF = (float*)outp;
        #pragma unroll
        for (int mt = 0; mt < 4; ++mt)
            #pragma unroll
            for (int nt = 0; nt < 4; ++nt)
                #pragma unroll
                for (int r = 0; r < 4; ++r) {
                    int c = bm * 128 + wm + mt * 16 + l4 * 4 + r;   // channel
                    int m = bn * 128 + wn + nt * 16 + l15;          // b*4096+n
                    int b = m >> 12, n = m & 4095;
                    size_t idx = ((size_t)(b * 512 + c)) * 4096 + n;
                    outF[idx] = acc[mt][nt][r] + bias[c] + resid[idx];
                }
    }
}

// ---------------------------------------------------------------------------
// 4. V -> Vt : [B*N, 512] (head cols) -> [bh, 64 d, 4096 n]
// ---------------------------------------------------------------------------
__global__ __launch_bounds__(256) void transpose_v(
    const unsigned short* __restrict__ v, unsigned short* __restrict__ vt)
{
    const int bh = blockIdx.y, b = bh >> 3, h = bh & 7;
    const int n0 = blockIdx.x * 64;
    __shared__ __attribute__((aligned(16))) unsigned short tile[64][72];
    const int t = threadIdx.x;
    #pragma unroll
    for (int j = 0; j < 2; ++j) {
        int chunk = j * 256 + t;          // 512: row nl(64) x 8 chunks of 8
        int nl = chunk >> 3, d8 = (chunk & 7) * 8;
        *(ushort8*)&tile[nl][d8] =
            *(const ushort8*)(v + ((size_t)(b * 4096 + n0 + nl)) * 512 + h * 64 + d8);
    }
    __syncthreads();
    #pragma unroll
    for (int j = 0; j < 2; ++j) {
        int chunk = j * 256 + t;          // 512: row d(64) x 8 chunks of 8
        int d = chunk >> 3, n8 = (chunk & 7) * 8;
        ushort8 val;
        #pragma unroll
        for (int i = 0; i < 8; ++i) val[i] = tile[n8 + i][d];
        *(ushort8*)(vt + ((size_t)(bh * 64 + d)) * 4096 + n0 + n8) = val;
    }
}

// ---------------------------------------------------------------------------
// 5. Flash attention. Block = 128 Q rows of one (b,h); 4 waves x 32 rows.
//    BN=128 keys/iter, 32 iters. S via 16x16x32 MFMA (Q,K both A-like layout
//    from row-major [rows,64]); softmax online in fp32; P through LDS
//    (per-16-row tile) to A-layout; PV with Vt fragments cached in registers.
// ---------------------------------------------------------------------------
__global__ __launch_bounds__(256, 2) void attn_kernel(
    const unsigned short* __restrict__ q, const unsigned short* __restrict__ kk,
    const unsigned short* __restrict__ vt, unsigned short* __restrict__ o)
{
    __shared__ __attribute__((aligned(16))) unsigned short Ks[128][72];
    __shared__ __attribute__((aligned(16))) unsigned short Vts[64][136];
    __shared__ __attribute__((aligned(16))) unsigned short Ps[64][136];

    const int bh = blockIdx.y, b = bh >> 3, h = bh & 7;
    const int row0 = blockIdx.x * 128;
    const int t = threadIdx.x, w = t >> 6, lane = t & 63;
    const int l15 = lane & 15, l4 = lane >> 4;

    const unsigned short* Qg = q  + ((size_t)(b * 4096 + row0)) * 512 + h * 64;
    const unsigned short* Kg = kk + ((size_t)(b * 4096)) * 512 + h * 64;
    const unsigned short* Vg = vt + ((size_t)bh) * 64 * 4096;

    bf16x8 qf[2][2];
    #pragma unroll
    for (int rt = 0; rt < 2; ++rt)
        #pragma unroll
        for (int ks = 0; ks < 2; ++ks)
            qf[rt][ks] = *(const bf16x8*)(Qg + (size_t)(w * 32 + rt * 16 + l15) * 512 + ks * 32 + l4 * 8);

    f32x4 Oacc[2][4] = {};
    float mi[2][4], li[2][4];
    #pragma unroll
    for (int rt = 0; rt < 2; ++rt)
        #pragma unroll
        for (int r = 0; r < 4; ++r) { mi[rt][r] = -1e30f; li[rt][r] = 0.f; }

    const float cs = 0.125f * 1.44269504088896340736f;  // scale * log2(e)
    const f32x4 Z0 = {0.f, 0.f, 0.f, 0.f};

    for (int kt = 0; kt < 32; ++kt) {
        const int kn0 = kt * 128;
        __syncthreads();
        #pragma unroll
        for (int j = 0; j < 4; ++j) {            // K tile: 128 rows x 64
            int chunk = j * 256 + t;
            int row = chunk >> 3, c8 = (chunk & 7) * 8;
            *(ushort8*)&Ks[row][c8] = *(const ushort8*)(Kg + (size_t)(kn0 + row) * 512 + c8);
        }
        #pragma unroll
        for (int j = 0; j < 4; ++j) {            // Vt tile: 64 rows x 128
            int chunk = j * 256 + t;
            int d = chunk >> 4, n8 = (chunk & 15) * 8;
            *(ushort8*)&Vts[d][n8] = *(const ushort8*)(Vg + (size_t)d * 4096 + kn0 + n8);
        }
        __syncthreads();

        // ---- S = (Q @ K^T), fp32 fragments (unscaled) ----
        f32x4 S[2][8];
        #pragma unroll
        for (int rt = 0; rt < 2; ++rt)
            #pragma unroll
            for (int ct = 0; ct < 8; ++ct) S[rt][ct] = Z0;

        #pragma unroll
        for (int ct = 0; ct < 8; ++ct) {
            bf16x8 b0 = *(const bf16x8*)&Ks[ct * 16 + l15][l4 * 8];
            bf16x8 b1 = *(const bf16x8*)&Ks[ct * 16 + l15][32 + l4 * 8];
            #pragma unroll
            for (int rt = 0; rt < 2; ++rt) {
                S[rt][ct] = __builtin_amdgcn_mfma_f32_16x16x32_bf16(qf[rt][0], b0, S[rt][ct], 0, 0, 0);
                S[rt][ct] = __builtin_amdgcn_mfma_f32_16x16x32_bf16(qf[rt][1], b1, S[rt][ct], 0, 0, 0);
            }
        }

        // ---- online softmax + PV, one 16-row tile (rt) at a time ----
        bf16x8 vfrag[4][4];
        #pragma unroll
        for (int rt = 0; rt < 2; ++rt) {
            #pragma unroll
            for (int r = 0; r < 4; ++r) {
                float tmax = S[rt][0][r];
                #pragma unroll
                for (int ct = 1; ct < 8; ++ct) tmax = fmaxf(tmax, S[rt][ct][r]);
                #pragma unroll
                for (int off = 8; off >= 1; off >>= 1)
                    tmax = fmaxf(tmax, __shfl_xor(tmax, off, 64));
                float mnew = fmaxf(mi[rt][r], tmax);
                float alpha = exp2f((mi[rt][r] - mnew) * cs);
                mi[rt][r] = mnew;
                float rowsum = 0.f;
                #pragma unroll
                for (int ct = 0; ct < 8; ++ct) {
                    float p = exp2f((S[rt][ct][r] - mnew) * cs);
                    rowsum += p;
                    Ps[w * 16 + l4 * 4 + r][ct * 16 + l15] = f2bf(p);
                }
                #pragma unroll
                for (int off = 8; off >= 1; off >>= 1)
                    rowsum += __shfl_xor(rowsum, off, 64);
                li[rt][r] = li[rt][r] * alpha + rowsum;
                #pragma unroll
                for (int nt = 0; nt < 4; ++nt) Oacc[rt][nt][r] *= alpha;
            }
            if (rt == 0) {      // load V fragments once, reuse for both rt
                #pragma unroll
                for (int ks = 0; ks < 4; ++ks)
                    #pragma unroll
                    for (int nt = 0; nt < 4; ++nt)
                        vfrag[ks][nt] = *(const bf16x8*)&Vts[nt * 16 + l15][ks * 32 + l4 * 8];
            }
            #pragma unroll
            for (int ks = 0; ks < 4; ++ks) {
                bf16x8 af = *(const bf16x8*)&Ps[w * 16 + l15][ks * 32 + l4 * 8];
                #pragma unroll
                for (int nt = 0; nt < 4; ++nt)
                    Oacc[rt][nt] = __builtin_amdgcn_mfma_f32_16x16x32_bf16(
                        af, vfrag[ks][nt], Oacc[rt][nt], 0, 0, 0);
            }
        }
    }

    unsigned short* Og = o + ((size_t)(b * 4096 + row0)) * 512 + h * 64;
    #pragma unroll
    for (int rt = 0; rt < 2; ++rt)
        #pragma unroll
        for (int nt = 0; nt < 4; ++nt)
            #pragma unroll
            for (int r = 0; r < 4; ++r) {
                float v = Oacc[rt][nt][r] / li[rt][r];
                Og[(size_t)(w * 32 + rt * 16 + l4 * 4 + r) * 512 + nt * 16 + l15] = f2bf(v);
            }
}

// ---------------------------------------------------------------------------
// launch
// ---------------------------------------------------------------------------
extern "C" void kernel_launch(void* const* d_in, const int* in_sizes, int n_in,
                              void* d_out, int out_size, void* d_ws, size_t ws_size,
                              hipStream_t stream) {
    const float* x     = (const float*)d_in[0];
    const float* gamma = (const float*)d_in[1];
    const float* beta  = (const float*)d_in[2];
    const float* Wq    = (const float*)d_in[3];
    const float* bq    = (const float*)d_in[4];
    const float* Wk    = (const float*)d_in[5];
    const float* bk    = (const float*)d_in[6];
    const float* Wv    = (const float*)d_in[7];
    const float* bv    = (const float*)d_in[8];
    const float* Wo    = (const float*)d_in[9];
    const float* bo    = (const float*)d_in[10];
    float* out = (float*)d_out;

    char* ws = (char*)d_ws;
    const size_t MB = 1024 * 1024;
    unsigned short* h   = (unsigned short*)(ws);            // 8 MB, reused as O
    unsigned short* qb  = (unsigned short*)(ws + 8 * MB);   // 8 MB
    unsigned short* kb  = (unsigned short*)(ws + 16 * MB);  // 8 MB
    unsigned short* vb  = (unsigned short*)(ws + 24 * MB);  // 8 MB
    unsigned short* vtb = (unsigned short*)(ws + 32 * MB);  // 8 MB
    unsigned short* wb  = (unsigned short*)(ws + 40 * MB);  // 2 MB (Wq|Wk|Wv|Wo bf16)

    convert_w<<<dim3(4096), dim3(256), 0, stream>>>(Wq, Wk, Wv, Wo, wb);
    groupnorm_kernel<<<dim3(64), dim3(256), 0, stream>>>(x, gamma, beta, h);

    // q/k/v = h @ W^T + b   (M=8192, N=512, K=512)
    gemm_bt<0><<<dim3(4, 64), dim3(256), 0, stream>>>(h, wb,          bq, nullptr, qb, 8192, 512, 512);
    gemm_bt<0><<<dim3(4, 64), dim3(256), 0, stream>>>(h, wb + 262144, bk, nullptr, kb, 8192, 512, 512);
    gemm_bt<0><<<dim3(4, 64), dim3(256), 0, stream>>>(h, wb + 524288, bv, nullptr, vb, 8192, 512, 512);

    transpose_v<<<dim3(64, 16), dim3(256), 0, stream>>>(vb, vtb);

    attn_kernel<<<dim3(32, 16), dim3(256), 0, stream>>>(qb, kb, vtb, h);  // O -> h buffer

    // out[b,c,n] = x + (O @ Wo^T + bo)^T : computed as C[c, m] with A=Wo, Bt=O
    gemm_bt<1><<<dim3(64, 4), dim3(256), 0, stream>>>(wb + 786432, h, bo, x, out, 512, 8192, 512);
}

// Round 2
// 301.592 us; speedup vs baseline: 1.2976x; 1.2976x over previous
//
#include <hip/hip_runtime.h>
#include <cstdint>
#include <cstddef>

typedef __bf16 bf16x8 __attribute__((ext_vector_type(8)));
typedef __bf16 bf16x4 __attribute__((ext_vector_type(4)));
typedef float f32x4 __attribute__((ext_vector_type(4)));
typedef unsigned short ushort8 __attribute__((ext_vector_type(8)));
typedef float f4 __attribute__((ext_vector_type(4)));

__device__ __forceinline__ unsigned short f2bf(float f) {
    __bf16 b = (__bf16)f;
    return *(unsigned short*)&b;
}

#define GLL(g, l) __builtin_amdgcn_global_load_lds( \
    (__attribute__((address_space(1))) void*)(g), \
    (__attribute__((address_space(3))) void*)(l), 16, 0, 0)

// ---------------------------------------------------------------------------
// 1. Convert the four 512x512 fp32 weight matrices to bf16 (concatenated).
// ---------------------------------------------------------------------------
__global__ __launch_bounds__(256) void convert_w(
    const float* __restrict__ wq, const float* __restrict__ wk,
    const float* __restrict__ wv, const float* __restrict__ wo,
    unsigned short* __restrict__ out)
{
    int i = blockIdx.x * 256 + threadIdx.x;
    const float* src = (i < 262144) ? wq : (i < 524288) ? wk : (i < 786432) ? wv : wo;
    out[i] = f2bf(src[i & 262143]);
}

// ---------------------------------------------------------------------------
// 2. GroupNorm -> h bf16 in [B*N, C] layout (transposed).
// ---------------------------------------------------------------------------
__global__ __launch_bounds__(256) void groupnorm_kernel(
    const float* __restrict__ x, const float* __restrict__ gamma,
    const float* __restrict__ beta, unsigned short* __restrict__ h)
{
    const int bid = blockIdx.x;           // 64 = 2 batches * 32 groups
    const int b = bid >> 5, g = bid & 31;
    const float* xg = x + ((size_t)(b * 512 + g * 16)) * 4096;
    const int t = threadIdx.x;

    float s = 0.f, sq = 0.f;
    const f4* xv = (const f4*)xg;
    for (int i = t; i < 16384; i += 256) {
        f4 v = xv[i];
        s  += v.x + v.y + v.z + v.w;
        sq += v.x * v.x + v.y * v.y + v.z * v.z + v.w * v.w;
    }
    #pragma unroll
    for (int off = 32; off > 0; off >>= 1) {
        s  += __shfl_xor(s, off, 64);
        sq += __shfl_xor(sq, off, 64);
    }
    __shared__ float red[8];
    __shared__ float stats[2];
    const int w = t >> 6, lane = t & 63;
    if (lane == 0) { red[w] = s; red[4 + w] = sq; }
    __syncthreads();
    if (t == 0) {
        float ts = red[0] + red[1] + red[2] + red[3];
        float tq = red[4] + red[5] + red[6] + red[7];
        float mean = ts * (1.f / 65536.f);
        float var  = tq * (1.f / 65536.f) - mean * mean;
        stats[0] = mean;
        stats[1] = rsqrtf(var + 1e-5f);
    }
    __syncthreads();
    const float mean = stats[0], rstd = stats[1];
    float gm[16], bt[16];
    #pragma unroll
    for (int c = 0; c < 16; ++c) {
        gm[c] = gamma[g * 16 + c] * rstd;
        bt[c] = beta[g * 16 + c];
    }
    for (int nt = 0; nt < 16; ++nt) {
        const int n = nt * 256 + t;
        ushort8 v0, v1;
        #pragma unroll
        for (int c = 0; c < 8; ++c)
            v0[c] = f2bf((xg[(size_t)c * 4096 + n] - mean) * gm[c] + bt[c]);
        #pragma unroll
        for (int c = 8; c < 16; ++c)
            v1[c - 8] = f2bf((xg[(size_t)c * 4096 + n] - mean) * gm[c] + bt[c]);
        unsigned short* dst = h + ((size_t)(b * 4096 + n)) * 512 + g * 16;
        *(ushort8*)dst = v0;
        *(ushort8*)(dst + 8) = v1;
    }
}

// ---------------------------------------------------------------------------
// 3. bf16 GEMM  C[i,j] = sum_k A[i,k]*Bt[j,k] (+bias, +epilogue)
//    MODE 0: out bf16 [i*N + j]; bias selected among 3 ptrs by j>>9 (fused QKV)
//    MODE 1: out fp32 transposed to [B,C,H,W] with residual, bias by i (final)
//    128x128 tile, BK=32, 4 waves, 16x16x32 MFMA, global_load_lds staging.
// ---------------------------------------------------------------------------
template <int MODE>
__global__ __launch_bounds__(256, 2) void gemm_bt(
    const unsigned short* __restrict__ A,   // [M,K] bf16
    const unsigned short* __restrict__ Bt,  // [N,K] bf16
    const float* __restrict__ bias0,
    const float* __restrict__ bias1,
    const float* __restrict__ bias2,
    const float* __restrict__ resid,
    void* __restrict__ outp,
    int M, int N, int K)
{
    __shared__ __attribute__((aligned(16))) unsigned short As[128 * 32];
    __shared__ __attribute__((aligned(16))) unsigned short Bs[128 * 32];
    const int t = threadIdx.x;
    const int w = t >> 6, lane = t & 63;
    const int l15 = lane & 15, l4 = lane >> 4;
    const int bm = blockIdx.y, bn = blockIdx.x;
    const int wm = (w >> 1) * 64, wn = (w & 1) * 64;

    f32x4 acc[4][4] = {};

    const int srow = t >> 2;            // 0..63
    const int sc8  = (t & 3) * 8;       // 0,8,16,24

    const unsigned short* gA0 = A  + (size_t)(bm * 128 + srow) * K + sc8;
    const unsigned short* gA1 = gA0 + (size_t)64 * K;
    const unsigned short* gB0 = Bt + (size_t)(bn * 128 + srow) * K + sc8;
    const unsigned short* gB1 = gB0 + (size_t)64 * K;
    unsigned short* lA0 = &As[w * 512];
    unsigned short* lA1 = &As[2048 + w * 512];
    unsigned short* lB0 = &Bs[w * 512];
    unsigned short* lB1 = &Bs[2048 + w * 512];

    for (int k0 = 0; k0 < K; k0 += 32) {
        __syncthreads();
        GLL(gA0 + k0, lA0);
        GLL(gA1 + k0, lA1);
        GLL(gB0 + k0, lB0);
        GLL(gB1 + k0, lB1);
        __syncthreads();

        bf16x8 af[4], bfr[4];
        #pragma unroll
        for (int mt = 0; mt < 4; ++mt)
            af[mt] = *(const bf16x8*)&As[(wm + mt * 16 + l15) * 32 + l4 * 8];
        #pragma unroll
        for (int nt = 0; nt < 4; ++nt)
            bfr[nt] = *(const bf16x8*)&Bs[(wn + nt * 16 + l15) * 32 + l4 * 8];
        #pragma unroll
        for (int mt = 0; mt < 4; ++mt)
            #pragma unroll
            for (int nt = 0; nt < 4; ++nt)
                acc[mt][nt] = __builtin_amdgcn_mfma_f32_16x16x32_bf16(
                    af[mt], bfr[nt], acc[mt][nt], 0, 0, 0);
    }

    if (MODE == 0) {
        unsigned short* outB = (unsigned short*)outp;
        #pragma unroll
        for (int nt = 0; nt < 4; ++nt) {
            int col = bn * 128 + wn + nt * 16 + l15;
            const float* bp = (col < 512) ? bias0 : (col < 1024) ? bias1 : bias2;
            float bv = bp[col & 511];
            #pragma unroll
            for (int mt = 0; mt < 4; ++mt)
                #pragma unroll
                for (int r = 0; r < 4; ++r) {
                    int row = bm * 128 + wm + mt * 16 + l4 * 4 + r;
                    outB[(size_t)row * N + col] = f2bf(acc[mt][nt][r] + bv);
                }
        }
    } else {
        float* outF = (float*)outp;
        #pragma unroll
        for (int mt = 0; mt < 4; ++mt)
            #pragma unroll
            for (int nt = 0; nt < 4; ++nt)
                #pragma unroll
                for (int r = 0; r < 4; ++r) {
                    int c = bm * 128 + wm + mt * 16 + l4 * 4 + r;   // channel
                    int m = bn * 128 + wn + nt * 16 + l15;          // b*4096+n
                    int b = m >> 12, n = m & 4095;
                    size_t idx = ((size_t)(b * 512 + c)) * 4096 + n;
                    outF[idx] = acc[mt][nt][r] + bias0[c] + resid[idx];
                }
    }
}

// ---------------------------------------------------------------------------
// 4. V -> Vt : v columns of fused qkv [B*N, 1536] -> [bh, 64 d, 4096 n]
// ---------------------------------------------------------------------------
__global__ __launch_bounds__(256) void transpose_v(
    const unsigned short* __restrict__ qkv, unsigned short* __restrict__ vt)
{
    const int bh = blockIdx.y, b = bh >> 3, h = bh & 7;
    const int n0 = blockIdx.x * 64;
    __shared__ __attribute__((aligned(16))) unsigned short tile[64][72];
    const int t = threadIdx.x;
    #pragma unroll
    for (int j = 0; j < 2; ++j) {
        int chunk = j * 256 + t;
        int nl = chunk >> 3, d8 = (chunk & 7) * 8;
        *(ushort8*)&tile[nl][d8] =
            *(const ushort8*)(qkv + ((size_t)(b * 4096 + n0 + nl)) * 1536 + 1024 + h * 64 + d8);
    }
    __syncthreads();
    #pragma unroll
    for (int j = 0; j < 2; ++j) {
        int chunk = j * 256 + t;
        int d = chunk >> 3, n8 = (chunk & 7) * 8;
        ushort8 val;
        #pragma unroll
        for (int i = 0; i < 8; ++i) val[i] = tile[n8 + i][d];
        *(ushort8*)(vt + ((size_t)(bh * 64 + d)) * 4096 + n0 + n8) = val;
    }
}

// ---------------------------------------------------------------------------
// 5. Flash attention, S^T layout.
//    Block = 128 Q rows of one (b,h); 4 waves x 32 rows (2 rt tiles of 16).
//    S^T = mfma(K_frag, Q_frag): each lane's 32 S values belong to ONE q row
//    (col=lane&15) -> in-register row stats + 2 shuffles; P packed as b64
//    into [q][key] rows = A-layout for PV.
// ---------------------------------------------------------------------------
__global__ __launch_bounds__(256, 2) void attn_kernel(
    const unsigned short* __restrict__ qkv, const unsigned short* __restrict__ vt,
    unsigned short* __restrict__ o)
{
    __shared__ __attribute__((aligned(16))) unsigned short Ks[128][72];
    __shared__ __attribute__((aligned(16))) unsigned short Vts[64][136];
    __shared__ __attribute__((aligned(16))) unsigned short Ps[64][136];

    const int bh = blockIdx.y, b = bh >> 3, h = bh & 7;
    const int row0 = blockIdx.x * 128;
    const int t = threadIdx.x, w = t >> 6, lane = t & 63;
    const int l15 = lane & 15, l4 = lane >> 4;

    const unsigned short* Qg = qkv + ((size_t)(b * 4096 + row0)) * 1536 + h * 64;
    const unsigned short* Kg = qkv + ((size_t)(b * 4096)) * 1536 + 512 + h * 64;
    const unsigned short* Vg = vt + ((size_t)bh) * 64 * 4096;

    // Q fragments (B-operand layout): q row = l15, d chunk = l4*8
    bf16x8 qf[2][2];
    #pragma unroll
    for (int rt = 0; rt < 2; ++rt)
        #pragma unroll
        for (int ks = 0; ks < 2; ++ks)
            qf[rt][ks] = *(const bf16x8*)(Qg + (size_t)(w * 32 + rt * 16 + l15) * 1536 + ks * 32 + l4 * 8);

    f32x4 Oacc[2][4] = {};
    float mi[2] = {-1e30f, -1e30f};
    float li[2] = {0.f, 0.f};          // per-lane partial (this lane's key subset)

    const float cs = 0.125f * 1.44269504088896340736f;  // scale * log2(e)
    const f32x4 Z0 = {0.f, 0.f, 0.f, 0.f};

    // precomputed staging addresses
    const unsigned short* gK = Kg + (size_t)(t >> 3) * 1536 + (t & 7) * 8;
    unsigned short* lK = &Ks[t >> 3][(t & 7) * 8];
    const unsigned short* gV = Vg + (size_t)(t >> 4) * 4096 + (t & 15) * 8;
    unsigned short* lV = &Vts[t >> 4][(t & 15) * 8];

    for (int kt = 0; kt < 32; ++kt) {
        const int kn0 = kt * 128;
        __syncthreads();
        #pragma unroll
        for (int j = 0; j < 4; ++j)
            *(ushort8*)(lK + j * 32 * 72) = *(const ushort8*)(gK + (size_t)(kn0 + j * 32) * 1536);
        #pragma unroll
        for (int j = 0; j < 4; ++j)
            *(ushort8*)(lV + j * 16 * 136) = *(const ushort8*)(gV + kn0 + (size_t)j * 16 * 4096);
        __syncthreads();

        // ---- S^T = K @ Q^T : St[rt][kc] holds keys kc*16+l4*4+r, q = rt*16+l15
        f32x4 St[2][8];
        #pragma unroll
        for (int rt = 0; rt < 2; ++rt)
            #pragma unroll
            for (int kc = 0; kc < 8; ++kc) St[rt][kc] = Z0;

        #pragma unroll
        for (int kc = 0; kc < 8; ++kc) {
            bf16x8 k0 = *(const bf16x8*)&Ks[kc * 16 + l15][l4 * 8];
            bf16x8 k1 = *(const bf16x8*)&Ks[kc * 16 + l15][32 + l4 * 8];
            St[0][kc] = __builtin_amdgcn_mfma_f32_16x16x32_bf16(k0, qf[0][0], St[0][kc], 0, 0, 0);
            St[0][kc] = __builtin_amdgcn_mfma_f32_16x16x32_bf16(k1, qf[0][1], St[0][kc], 0, 0, 0);
            St[1][kc] = __builtin_amdgcn_mfma_f32_16x16x32_bf16(k0, qf[1][0], St[1][kc], 0, 0, 0);
            St[1][kc] = __builtin_amdgcn_mfma_f32_16x16x32_bf16(k1, qf[1][1], St[1][kc], 0, 0, 0);
        }

        bf16x8 vfrag[4][4];
        #pragma unroll
        for (int rt = 0; rt < 2; ++rt) {
            // row max: 32 in-register values all belong to q row rt*16+l15
            f32x4 m4 = St[rt][0];
            #pragma unroll
            for (int kc = 1; kc < 8; ++kc) {
                m4[0] = fmaxf(m4[0], St[rt][kc][0]);
                m4[1] = fmaxf(m4[1], St[rt][kc][1]);
                m4[2] = fmaxf(m4[2], St[rt][kc][2]);
                m4[3] = fmaxf(m4[3], St[rt][kc][3]);
            }
            float m = fmaxf(fmaxf(m4[0], m4[1]), fmaxf(m4[2], m4[3]));
            m = fmaxf(m, __shfl_xor(m, 16, 64));
            m = fmaxf(m, __shfl_xor(m, 32, 64));
            float mnew = fmaxf(mi[rt], m);
            float a = exp2f((mi[rt] - mnew) * cs);
            mi[rt] = mnew;
            float rs = 0.f;
            #pragma unroll
            for (int kc = 0; kc < 8; ++kc) {
                float p0 = exp2f((St[rt][kc][0] - mnew) * cs);
                float p1 = exp2f((St[rt][kc][1] - mnew) * cs);
                float p2 = exp2f((St[rt][kc][2] - mnew) * cs);
                float p3 = exp2f((St[rt][kc][3] - mnew) * cs);
                rs += (p0 + p1) + (p2 + p3);
                bf16x4 pk;
                pk[0] = (__bf16)p0; pk[1] = (__bf16)p1;
                pk[2] = (__bf16)p2; pk[3] = (__bf16)p3;
                *(bf16x4*)&Ps[w * 16 + l15][kc * 16 + l4 * 4] = pk;   // b64 store
            }
            li[rt] = li[rt] * a + rs;

            if (rt == 0) {      // V fragments once, reused for both rt
                #pragma unroll
                for (int ks = 0; ks < 4; ++ks)
                    #pragma unroll
                    for (int nt = 0; nt < 4; ++nt)
                        vfrag[ks][nt] = *(const bf16x8*)&Vts[nt * 16 + l15][ks * 32 + l4 * 8];
            }
            // rescale O (rows q = l4*4+r): broadcast alpha from stat lanes
            #pragma unroll
            for (int r = 0; r < 4; ++r) {
                float av = __shfl(a, l4 * 4 + r, 64);
                #pragma unroll
                for (int nt = 0; nt < 4; ++nt) Oacc[rt][nt][r] *= av;
            }
            // PV
            #pragma unroll
            for (int ks = 0; ks < 4; ++ks) {
                bf16x8 af = *(const bf16x8*)&Ps[w * 16 + l15][ks * 32 + l4 * 8];
                #pragma unroll
                for (int nt = 0; nt < 4; ++nt)
                    Oacc[rt][nt] = __builtin_amdgcn_mfma_f32_16x16x32_bf16(
                        af, vfrag[ks][nt], Oacc[rt][nt], 0, 0, 0);
            }
        }
    }

    unsigned short* Og = o + ((size_t)(b * 4096 + row0)) * 512 + h * 64;
    #pragma unroll
    for (int rt = 0; rt < 2; ++rt) {
        float s = li[rt];
        s += __shfl_xor(s, 16, 64);
        s += __shfl_xor(s, 32, 64);
        #pragma unroll
        for (int r = 0; r < 4; ++r) {
            float inv = 1.f / __shfl(s, l4 * 4 + r, 64);
            #pragma unroll
            for (int nt = 0; nt < 4; ++nt)
                Og[(size_t)(w * 32 + rt * 16 + l4 * 4 + r) * 512 + nt * 16 + l15] =
                    f2bf(Oacc[rt][nt][r] * inv);
        }
    }
}

// ---------------------------------------------------------------------------
// launch
// ---------------------------------------------------------------------------
extern "C" void kernel_launch(void* const* d_in, const int* in_sizes, int n_in,
                              void* d_out, int out_size, void* d_ws, size_t ws_size,
                              hipStream_t stream) {
    const float* x     = (const float*)d_in[0];
    const float* gamma = (const float*)d_in[1];
    const float* beta  = (const float*)d_in[2];
    const float* Wq    = (const float*)d_in[3];
    const float* bq    = (const float*)d_in[4];
    const float* Wk    = (const float*)d_in[5];
    const float* bk    = (const float*)d_in[6];
    const float* Wv    = (const float*)d_in[7];
    const float* bv    = (const float*)d_in[8];
    const float* Wo    = (const float*)d_in[9];
    const float* bo    = (const float*)d_in[10];
    float* out = (float*)d_out;

    char* ws = (char*)d_ws;
    const size_t MB = 1024 * 1024;
    unsigned short* h   = (unsigned short*)(ws);            // 8 MB, reused as O
    unsigned short* qkv = (unsigned short*)(ws + 8 * MB);   // 24 MB [8192][1536]
    unsigned short* vtb = (unsigned short*)(ws + 32 * MB);  // 8 MB
    unsigned short* wb  = (unsigned short*)(ws + 40 * MB);  // 2 MB (Wq|Wk|Wv|Wo)

    convert_w<<<dim3(4096), dim3(256), 0, stream>>>(Wq, Wk, Wv, Wo, wb);
    groupnorm_kernel<<<dim3(64), dim3(256), 0, stream>>>(x, gamma, beta, h);

    // fused qkv = h @ [Wq;Wk;Wv]^T + b   (M=8192, N=1536, K=512)
    gemm_bt<0><<<dim3(12, 64), dim3(256), 0, stream>>>(
        h, wb, bq, bk, bv, nullptr, qkv, 8192, 1536, 512);

    transpose_v<<<dim3(64, 16), dim3(256), 0, stream>>>(qkv, vtb);

    attn_kernel<<<dim3(32, 16), dim3(256), 0, stream>>>(qkv, vtb, h);  // O -> h

    // out[b,c,n] = x + (O @ Wo^T + bo)^T : C[c, m] with A=Wo, Bt=O
    gemm_bt<1><<<dim3(64, 4), dim3(256), 0, stream>>>(
        wb + 786432, h, bo, nullptr, nullptr, x, out, 512, 8192, 512);
}

// Round 4
// 235.020 us; speedup vs baseline: 1.6652x; 1.2833x over previous
//
#include <hip/hip_runtime.h>
#include <cstdint>
#include <cstddef>

typedef __bf16 bf16x8 __attribute__((ext_vector_type(8)));
typedef float f32x4 __attribute__((ext_vector_type(4)));
typedef float f32x16 __attribute__((ext_vector_type(16)));
typedef unsigned short ushort8 __attribute__((ext_vector_type(8)));
typedef float f4 __attribute__((ext_vector_type(4)));

__device__ __forceinline__ unsigned short f2bf(float f) {
    __bf16 b = (__bf16)f;
    return *(unsigned short*)&b;
}
__device__ __forceinline__ unsigned pk2bf(float a, float b) {
    __bf16 x = (__bf16)a, y = (__bf16)b;
    unsigned short ux = *(unsigned short*)&x, uy = *(unsigned short*)&y;
    return (unsigned)ux | ((unsigned)uy << 16);
}

#if __has_builtin(__builtin_amdgcn_exp2f)
#define EXP2(x) __builtin_amdgcn_exp2f(x)
#else
#define EXP2(x) exp2f(x)
#endif

// exchange high 32 lanes of x with low 32 lanes of y (v_permlane32_swap_b32)
__device__ __forceinline__ void pl32swap(unsigned& x, unsigned& y) {
#if __has_builtin(__builtin_amdgcn_permlane32_swap)
    auto r = __builtin_amdgcn_permlane32_swap(x, y, false, false);
    x = r[0]; y = r[1];
#else
    unsigned xs = (unsigned)__shfl_xor((int)x, 32, 64);
    unsigned ys = (unsigned)__shfl_xor((int)y, 32, 64);
    bool lo = ((threadIdx.x & 63) < 32);
    unsigned nx = lo ? x : ys;
    unsigned ny = lo ? xs : y;
    x = nx; y = ny;
#endif
}

#define GLL(g, l) __builtin_amdgcn_global_load_lds( \
    (__attribute__((address_space(1))) void*)(g), \
    (__attribute__((address_space(3))) void*)(l), 16, 0, 0)

#define CS 0.18033688011112042f   /* 0.125 * log2(e) */

// ---------------------------------------------------------------------------
// 1. Convert the four 512x512 fp32 weight matrices to bf16 (concatenated).
// ---------------------------------------------------------------------------
__global__ __launch_bounds__(256) void convert_w(
    const float* __restrict__ wq, const float* __restrict__ wk,
    const float* __restrict__ wv, const float* __restrict__ wo,
    unsigned short* __restrict__ out)
{
    int i = blockIdx.x * 256 + threadIdx.x;
    const float* src = (i < 262144) ? wq : (i < 524288) ? wk : (i < 786432) ? wv : wo;
    out[i] = f2bf(src[i & 262143]);
}

// ---------------------------------------------------------------------------
// 2a. GroupNorm stats: grid (4 quarters, 64 b*g); partial sums -> part[bg*8+q*2]
// ---------------------------------------------------------------------------
__global__ __launch_bounds__(256) void gn_stats(
    const float* __restrict__ x, float* __restrict__ part)
{
    const int q = blockIdx.x, bg = blockIdx.y;
    const f4* xv = (const f4*)(x + (size_t)bg * 65536 + q * 16384);
    float s = 0.f, sq = 0.f;
    for (int i = threadIdx.x; i < 4096; i += 256) {
        f4 v = xv[i];
        s  += v.x + v.y + v.z + v.w;
        sq += v.x * v.x + v.y * v.y + v.z * v.z + v.w * v.w;
    }
    #pragma unroll
    for (int off = 32; off > 0; off >>= 1) {
        s  += __shfl_xor(s, off, 64);
        sq += __shfl_xor(sq, off, 64);
    }
    __shared__ float red[8];
    const int w = threadIdx.x >> 6, lane = threadIdx.x & 63;
    if (lane == 0) { red[w] = s; red[4 + w] = sq; }
    __syncthreads();
    if (threadIdx.x == 0) {
        part[(bg * 4 + q) * 2]     = red[0] + red[1] + red[2] + red[3];
        part[(bg * 4 + q) * 2 + 1] = red[4] + red[5] + red[6] + red[7];
    }
}

// ---------------------------------------------------------------------------
// 2b. GroupNorm apply -> h bf16 in [B*N, C] layout.
// ---------------------------------------------------------------------------
__global__ __launch_bounds__(256) void gn_apply(
    const float* __restrict__ x, const float* __restrict__ gamma,
    const float* __restrict__ beta, const float* __restrict__ part,
    unsigned short* __restrict__ h)
{
    const int q = blockIdx.x, bg = blockIdx.y;
    const int b = bg >> 5, g = bg & 31;
    float s = 0.f, sq = 0.f;
    #pragma unroll
    for (int j = 0; j < 4; ++j) {
        s  += part[(bg * 4 + j) * 2];
        sq += part[(bg * 4 + j) * 2 + 1];
    }
    const float mean = s * (1.f / 65536.f);
    const float rstd = rsqrtf(sq * (1.f / 65536.f) - mean * mean + 1e-5f);

    float gm[16], bt[16];
    #pragma unroll
    for (int c = 0; c < 16; ++c) {
        gm[c] = gamma[g * 16 + c] * rstd;
        bt[c] = beta[g * 16 + c];
    }
    const float* xg = x + (size_t)bg * 65536;
    const int n0 = q * 1024 + threadIdx.x * 4;
    float val[16][4];
    #pragma unroll
    for (int c = 0; c < 16; ++c) {
        f4 v = *(const f4*)&xg[(size_t)c * 4096 + n0];
        val[c][0] = (v.x - mean) * gm[c] + bt[c];
        val[c][1] = (v.y - mean) * gm[c] + bt[c];
        val[c][2] = (v.z - mean) * gm[c] + bt[c];
        val[c][3] = (v.w - mean) * gm[c] + bt[c];
    }
    #pragma unroll
    for (int nn = 0; nn < 4; ++nn) {
        ushort8 v0, v1;
        #pragma unroll
        for (int c = 0; c < 8; ++c)  v0[c]     = f2bf(val[c][nn]);
        #pragma unroll
        for (int c = 8; c < 16; ++c) v1[c - 8] = f2bf(val[c][nn]);
        unsigned short* dst = h + ((size_t)(b * 4096 + n0 + nn)) * 512 + g * 16;
        *(ushort8*)dst = v0;
        *(ushort8*)(dst + 8) = v1;
    }
}

// ---------------------------------------------------------------------------
// 3. bf16 GEMM  C[i,j] = sum_k A[i,k]*Bt[j,k] (+bias, +epilogue)
//    MODE 0: out bf16 [i*N+j]; bias by j among 3 ptrs; Q cols (<512) pre-scaled
//            by CS so attention needs no per-element scale.
//    MODE 1: out fp32 transposed to [B,C,H,W] with residual, bias by i.
// ---------------------------------------------------------------------------
template <int MODE>
__global__ __launch_bounds__(256, 2) void gemm_bt(
    const unsigned short* __restrict__ A,   // [M,K] bf16
    const unsigned short* __restrict__ Bt,  // [N,K] bf16
    const float* __restrict__ bias0,
    const float* __restrict__ bias1,
    const float* __restrict__ bias2,
    const float* __restrict__ resid,
    void* __restrict__ outp,
    int M, int N, int K)
{
    __shared__ __attribute__((aligned(16))) unsigned short As[128 * 32];
    __shared__ __attribute__((aligned(16))) unsigned short Bs[128 * 32];
    const int t = threadIdx.x;
    const int w = t >> 6, lane = t & 63;
    const int l15 = lane & 15, l4 = lane >> 4;
    const int bm = blockIdx.y, bn = blockIdx.x;
    const int wm = (w >> 1) * 64, wn = (w & 1) * 64;

    f32x4 acc[4][4] = {};

    const int srow = t >> 2;
    const int sc8  = (t & 3) * 8;

    const unsigned short* gA0 = A  + (size_t)(bm * 128 + srow) * K + sc8;
    const unsigned short* gA1 = gA0 + (size_t)64 * K;
    const unsigned short* gB0 = Bt + (size_t)(bn * 128 + srow) * K + sc8;
    const unsigned short* gB1 = gB0 + (size_t)64 * K;
    unsigned short* lA0 = &As[w * 512];
    unsigned short* lA1 = &As[2048 + w * 512];
    unsigned short* lB0 = &Bs[w * 512];
    unsigned short* lB1 = &Bs[2048 + w * 512];

    for (int k0 = 0; k0 < K; k0 += 32) {
        __syncthreads();
        GLL(gA0 + k0, lA0);
        GLL(gA1 + k0, lA1);
        GLL(gB0 + k0, lB0);
        GLL(gB1 + k0, lB1);
        __syncthreads();

        bf16x8 af[4], bfr[4];
        #pragma unroll
        for (int mt = 0; mt < 4; ++mt)
            af[mt] = *(const bf16x8*)&As[(wm + mt * 16 + l15) * 32 + l4 * 8];
        #pragma unroll
        for (int nt = 0; nt < 4; ++nt)
            bfr[nt] = *(const bf16x8*)&Bs[(wn + nt * 16 + l15) * 32 + l4 * 8];
        #pragma unroll
        for (int mt = 0; mt < 4; ++mt)
            #pragma unroll
            for (int nt = 0; nt < 4; ++nt)
                acc[mt][nt] = __builtin_amdgcn_mfma_f32_16x16x32_bf16(
                    af[mt], bfr[nt], acc[mt][nt], 0, 0, 0);
    }

    if (MODE == 0) {
        unsigned short* outB = (unsigned short*)outp;
        #pragma unroll
        for (int nt = 0; nt < 4; ++nt) {
            int col = bn * 128 + wn + nt * 16 + l15;
            const float* bp = (col < 512) ? bias0 : (col < 1024) ? bias1 : bias2;
            float bv = bp[col & 511];
            float sc = (col < 512) ? CS : 1.0f;   // fold softmax scale into Q
            #pragma unroll
            for (int mt = 0; mt < 4; ++mt)
                #pragma unroll
                for (int r = 0; r < 4; ++r) {
                    int row = bm * 128 + wm + mt * 16 + l4 * 4 + r;
                    outB[(size_t)row * N + col] = f2bf((acc[mt][nt][r] + bv) * sc);
                }
        }
    } else {
        float* outF = (float*)outp;
        #pragma unroll
        for (int mt = 0; mt < 4; ++mt)
            #pragma unroll
            for (int nt = 0; nt < 4; ++nt)
                #pragma unroll
                for (int r = 0; r < 4; ++r) {
                    int c = bm * 128 + wm + mt * 16 + l4 * 4 + r;
                    int m = bn * 128 + wn + nt * 16 + l15;
                    int b = m >> 12, n = m & 4095;
                    size_t idx = ((size_t)(b * 512 + c)) * 4096 + n;
                    outF[idx] = acc[mt][nt][r] + bias0[c] + resid[idx];
                }
    }
}

// ---------------------------------------------------------------------------
// 4. V -> Vt : v columns of fused qkv [B*N, 1536] -> [bh, 64 d, 4096 n]
// ---------------------------------------------------------------------------
__global__ __launch_bounds__(256) void transpose_v(
    const unsigned short* __restrict__ qkv, unsigned short* __restrict__ vt)
{
    const int bh = blockIdx.y, b = bh >> 3, h = bh & 7;
    const int n0 = blockIdx.x * 64;
    __shared__ __attribute__((aligned(16))) unsigned short tile[64][72];
    const int t = threadIdx.x;
    #pragma unroll
    for (int j = 0; j < 2; ++j) {
        int chunk = j * 256 + t;
        int nl = chunk >> 3, d8 = (chunk & 7) * 8;
        *(ushort8*)&tile[nl][d8] =
            *(const ushort8*)(qkv + ((size_t)(b * 4096 + n0 + nl)) * 1536 + 1024 + h * 64 + d8);
    }
    __syncthreads();
    #pragma unroll
    for (int j = 0; j < 2; ++j) {
        int chunk = j * 256 + t;
        int d = chunk >> 3, n8 = (chunk & 7) * 8;
        ushort8 val;
        #pragma unroll
        for (int i = 0; i < 8; ++i) val[i] = tile[n8 + i][d];
        *(ushort8*)(vt + ((size_t)(bh * 64 + d)) * 4096 + n0 + n8) = val;
    }
}

// ---------------------------------------------------------------------------
// 5. Flash attention, 32x32x16 MFMA, 64 q-rows/wave, fixed-shift softmax.
//    Block = 2 waves x 64 q = 128 q of one (b,h). BN=64 keys/iter, 64 iters.
//    S^T = mfma(K_frag, Q_frag) -> C: col(lane&31)=q, row=key. exp2 only
//    (scale pre-folded into Q). P: C-layout -> PV B-operand via
//    v_permlane32_swap (no LDS round-trip). O^T accumulated in C-layout;
//    epilogue transposes via LDS for coalesced-ish [m][C] output.
// ---------------------------------------------------------------------------
__global__ __launch_bounds__(128, 1) void attn_kernel(
    const unsigned short* __restrict__ qkv, const unsigned short* __restrict__ vt,
    unsigned short* __restrict__ o)
{
    __shared__ __attribute__((aligned(16))) unsigned short Ks[64][72];
    __shared__ __attribute__((aligned(16))) unsigned short Vts[64][72];
    __shared__ __attribute__((aligned(16))) unsigned short Oepi[128][72];

    const int bh = blockIdx.y, b = bh >> 3, h = bh & 7;
    const int row0 = blockIdx.x * 128;
    const int t = threadIdx.x, w = t >> 6, lane = t & 63;
    const int l31 = lane & 31, h5 = lane >> 5;

    const unsigned short* Qg = qkv + ((size_t)(b * 4096 + row0 + w * 64)) * 1536 + h * 64;
    const unsigned short* Kg = qkv + ((size_t)(b * 4096)) * 1536 + 512 + h * 64;
    const unsigned short* Vg = vt + ((size_t)bh) * 64 * 4096;

    // Q fragments (B-operand, persistent): q=qt*32+l31, k(d)=kc*16+h5*8+j
    bf16x8 qf[2][4];
    #pragma unroll
    for (int qt = 0; qt < 2; ++qt)
        #pragma unroll
        for (int kc = 0; kc < 4; ++kc)
            qf[qt][kc] = *(const bf16x8*)(Qg + (size_t)(qt * 32 + l31) * 1536 + kc * 16 + h5 * 8);

    f32x16 Oacc[2][2] = {};      // [dt][qt], C-layout: col=q, row=d
    float li[2] = {0.f, 0.f};    // per-lane partial denominators

    // staging: 128 threads x 64 B for each of K (8 KB) and V^T (8 KB)
    const int sr = t >> 1, sc0 = (t & 1) * 32;
    const unsigned short* gK = Kg + (size_t)sr * 1536 + sc0;
    const unsigned short* gV = Vg + (size_t)sr * 4096 + sc0;
    unsigned short* lK = &Ks[sr][sc0];
    unsigned short* lV = &Vts[sr][sc0];

    ushort8 kr[4], vr[4];
    #pragma unroll
    for (int j = 0; j < 4; ++j) {
        kr[j] = *(const ushort8*)(gK + j * 8);
        vr[j] = *(const ushort8*)(gV + j * 8);
    }

    for (int kt = 0; kt < 64; ++kt) {
        __syncthreads();
        #pragma unroll
        for (int j = 0; j < 4; ++j) {
            *(ushort8*)(lK + j * 8) = kr[j];
            *(ushort8*)(lV + j * 8) = vr[j];
        }
        __syncthreads();
        if (kt < 63) {   // prefetch next tile into registers (hides L2 latency)
            const unsigned short* nk = gK + (size_t)(kt + 1) * 64 * 1536;
            const unsigned short* nv = gV + (kt + 1) * 64;
            #pragma unroll
            for (int j = 0; j < 4; ++j) {
                kr[j] = *(const ushort8*)(nk + j * 8);
                vr[j] = *(const ushort8*)(nv + j * 8);
            }
        }

        // ---- S^T tiles: St[qt][ct] = K(ct) @ Q(qt)^T, already scaled ----
        f32x16 St[2][2] = {};
        #pragma unroll
        for (int ct = 0; ct < 2; ++ct)
            #pragma unroll
            for (int kc = 0; kc < 4; ++kc) {
                bf16x8 kf = *(const bf16x8*)&Ks[ct * 32 + l31][kc * 16 + h5 * 8];
                St[0][ct] = __builtin_amdgcn_mfma_f32_32x32x16_bf16(kf, qf[0][kc], St[0][ct], 0, 0, 0);
                St[1][ct] = __builtin_amdgcn_mfma_f32_32x32x16_bf16(kf, qf[1][kc], St[1][ct], 0, 0, 0);
            }

        // ---- p = exp2(S'); accumulate per-lane row sums; pack to B-operand --
        union PU { unsigned u[4]; bf16x8 v; };
        PU pf[2][4];
        #pragma unroll
        for (int qt = 0; qt < 2; ++qt) {
            #pragma unroll
            for (int ct = 0; ct < 2; ++ct)
                #pragma unroll
                for (int r = 0; r < 16; ++r)
                    St[qt][ct][r] = EXP2(St[qt][ct][r]);
            float s0 = 0.f, s1 = 0.f;
            #pragma unroll
            for (int ct = 0; ct < 2; ++ct) {
                s0 += ((St[qt][ct][0] + St[qt][ct][1]) + (St[qt][ct][2] + St[qt][ct][3]))
                    + ((St[qt][ct][4] + St[qt][ct][5]) + (St[qt][ct][6] + St[qt][ct][7]));
                s1 += ((St[qt][ct][8] + St[qt][ct][9]) + (St[qt][ct][10] + St[qt][ct][11]))
                    + ((St[qt][ct][12] + St[qt][ct][13]) + (St[qt][ct][14] + St[qt][ct][15]));
            }
            li[qt] += s0 + s1;

            #pragma unroll
            for (int ct = 0; ct < 2; ++ct) {
                unsigned pk0 = pk2bf(St[qt][ct][0],  St[qt][ct][1]);
                unsigned pk1 = pk2bf(St[qt][ct][2],  St[qt][ct][3]);
                unsigned pk2 = pk2bf(St[qt][ct][4],  St[qt][ct][5]);
                unsigned pk3 = pk2bf(St[qt][ct][6],  St[qt][ct][7]);
                unsigned pk4 = pk2bf(St[qt][ct][8],  St[qt][ct][9]);
                unsigned pk5 = pk2bf(St[qt][ct][10], St[qt][ct][11]);
                unsigned pk6 = pk2bf(St[qt][ct][12], St[qt][ct][13]);
                unsigned pk7 = pk2bf(St[qt][ct][14], St[qt][ct][15]);
                pl32swap(pk0, pk2); pl32swap(pk1, pk3);   // keys ct*32 + 0..15
                pl32swap(pk4, pk6); pl32swap(pk5, pk7);   // keys ct*32 + 16..31
                pf[qt][ct * 2].u[0] = pk0; pf[qt][ct * 2].u[1] = pk1;
                pf[qt][ct * 2].u[2] = pk2; pf[qt][ct * 2].u[3] = pk3;
                pf[qt][ct * 2 + 1].u[0] = pk4; pf[qt][ct * 2 + 1].u[1] = pk5;
                pf[qt][ct * 2 + 1].u[2] = pk6; pf[qt][ct * 2 + 1].u[3] = pk7;
            }
        }

        // ---- O^T += V^T(dt) @ P^T(kk) ----
        #pragma unroll
        for (int kk = 0; kk < 4; ++kk)
            #pragma unroll
            for (int dt = 0; dt < 2; ++dt) {
                bf16x8 vf = *(const bf16x8*)&Vts[dt * 32 + l31][kk * 16 + h5 * 8];
                Oacc[dt][0] = __builtin_amdgcn_mfma_f32_32x32x16_bf16(vf, pf[0][kk].v, Oacc[dt][0], 0, 0, 0);
                Oacc[dt][1] = __builtin_amdgcn_mfma_f32_32x32x16_bf16(vf, pf[1][kk].v, Oacc[dt][1], 0, 0, 0);
            }
    }

    // ---- epilogue: normalize, transpose via LDS, store [m][C] ----
    #pragma unroll
    for (int qt = 0; qt < 2; ++qt) {
        float lf = li[qt] + __shfl_xor(li[qt], 32, 64);
        float inv = 1.f / lf;
        #pragma unroll
        for (int dt = 0; dt < 2; ++dt)
            #pragma unroll
            for (int p = 0; p < 8; ++p) {
                int d = dt * 32 + 2 * (p & 1) + 8 * (p >> 1) + 4 * h5;
                unsigned u = pk2bf(Oacc[dt][qt][2 * p] * inv, Oacc[dt][qt][2 * p + 1] * inv);
                *(unsigned*)&Oepi[w * 64 + qt * 32 + l31][d] = u;
            }
    }
    // same-wave read-back (no barrier needed), coalesced-ish 16B global stores
    unsigned short* Og = o + ((size_t)(b * 4096 + row0 + w * 64)) * 512 + h * 64;
    #pragma unroll
    for (int c8 = 0; c8 < 8; ++c8) {
        ushort8 val = *(const ushort8*)&Oepi[w * 64 + lane][c8 * 8];
        *(ushort8*)(Og + (size_t)lane * 512 + c8 * 8) = val;
    }
}

// ---------------------------------------------------------------------------
// launch
// ---------------------------------------------------------------------------
extern "C" void kernel_launch(void* const* d_in, const int* in_sizes, int n_in,
                              void* d_out, int out_size, void* d_ws, size_t ws_size,
                              hipStream_t stream) {
    const float* x     = (const float*)d_in[0];
    const float* gamma = (const float*)d_in[1];
    const float* beta  = (const float*)d_in[2];
    const float* Wq    = (const float*)d_in[3];
    const float* bq    = (const float*)d_in[4];
    const float* Wk    = (const float*)d_in[5];
    const float* bk    = (const float*)d_in[6];
    const float* Wv    = (const float*)d_in[7];
    const float* bv    = (const float*)d_in[8];
    const float* Wo    = (const float*)d_in[9];
    const float* bo    = (const float*)d_in[10];
    float* out = (float*)d_out;

    char* ws = (char*)d_ws;
    const size_t MB = 1024 * 1024;
    unsigned short* h      = (unsigned short*)(ws);            // 8 MB, reused as O
    unsigned short* qkv    = (unsigned short*)(ws + 8 * MB);   // 24 MB [8192][1536]
    unsigned short* vtb    = (unsigned short*)(ws + 32 * MB);  // 8 MB
    unsigned short* wb     = (unsigned short*)(ws + 40 * MB);  // 2 MB (Wq|Wk|Wv|Wo)
    float*          gnpart = (float*)(ws + 42 * MB);           // 2 KB

    convert_w<<<dim3(4096), dim3(256), 0, stream>>>(Wq, Wk, Wv, Wo, wb);
    gn_stats<<<dim3(4, 64), dim3(256), 0, stream>>>(x, gnpart);
    gn_apply<<<dim3(4, 64), dim3(256), 0, stream>>>(x, gamma, beta, gnpart, h);

    // fused qkv = h @ [Wq;Wk;Wv]^T + b  (Q cols pre-scaled by CS)
    gemm_bt<0><<<dim3(12, 64), dim3(256), 0, stream>>>(
        h, wb, bq, bk, bv, nullptr, qkv, 8192, 1536, 512);

    transpose_v<<<dim3(64, 16), dim3(256), 0, stream>>>(qkv, vtb);

    attn_kernel<<<dim3(32, 16), dim3(128), 0, stream>>>(qkv, vtb, h);  // O -> h

    // out[b,c,n] = x + (O @ Wo^T + bo)^T : C[c, m] with A=Wo, Bt=O
    gemm_bt<1><<<dim3(64, 4), dim3(256), 0, stream>>>(
        wb + 786432, h, bo, nullptr, nullptr, x, out, 512, 8192, 512);
}

// Round 5
// 221.364 us; speedup vs baseline: 1.7679x; 1.0617x over previous
//
#include <hip/hip_runtime.h>
#include <cstdint>
#include <cstddef>

typedef __bf16 bf16x8 __attribute__((ext_vector_type(8)));
typedef float f32x4 __attribute__((ext_vector_type(4)));
typedef float f32x16 __attribute__((ext_vector_type(16)));
typedef unsigned short ushort8 __attribute__((ext_vector_type(8)));
typedef unsigned u32x2 __attribute__((ext_vector_type(2)));
typedef float f4 __attribute__((ext_vector_type(4)));

__device__ __forceinline__ unsigned short f2bf(float f) {
    __bf16 b = (__bf16)f;
    return *(unsigned short*)&b;
}
__device__ __forceinline__ unsigned pk2bf(float a, float b) {
    __bf16 x = (__bf16)a, y = (__bf16)b;
    unsigned short ux = *(unsigned short*)&x, uy = *(unsigned short*)&y;
    return (unsigned)ux | ((unsigned)uy << 16);
}
__device__ __forceinline__ float bf2f(unsigned short u) {
    union { unsigned u; float f; } v; v.u = ((unsigned)u) << 16; return v.f;
}

#if __has_builtin(__builtin_amdgcn_exp2f)
#define EXP2(x) __builtin_amdgcn_exp2f(x)
#else
#define EXP2(x) exp2f(x)
#endif

// exchange high 32 lanes of x with low 32 lanes of y (v_permlane32_swap_b32)
__device__ __forceinline__ void pl32swap(unsigned& x, unsigned& y) {
#if __has_builtin(__builtin_amdgcn_permlane32_swap)
    auto r = __builtin_amdgcn_permlane32_swap(x, y, false, false);
    x = r[0]; y = r[1];
#else
    unsigned xs = (unsigned)__shfl_xor((int)x, 32, 64);
    unsigned ys = (unsigned)__shfl_xor((int)y, 32, 64);
    bool lo = ((threadIdx.x & 63) < 32);
    unsigned nx = lo ? x : ys;
    unsigned ny = lo ? xs : y;
    x = nx; y = ny;
#endif
}

#define GLL(g, l) __builtin_amdgcn_global_load_lds( \
    (__attribute__((address_space(1))) void*)(g), \
    (__attribute__((address_space(3))) void*)(l), 16, 0, 0)

#define CS 0.18033688011112042f   /* 0.125 * log2(e) */

// ---------------------------------------------------------------------------
// 1. Convert the four 512x512 fp32 weight matrices to bf16 (concatenated).
// ---------------------------------------------------------------------------
__global__ __launch_bounds__(256) void convert_w(
    const float* __restrict__ wq, const float* __restrict__ wk,
    const float* __restrict__ wv, const float* __restrict__ wo,
    unsigned short* __restrict__ out)
{
    int i = blockIdx.x * 256 + threadIdx.x;
    const float* src = (i < 262144) ? wq : (i < 524288) ? wk : (i < 786432) ? wv : wo;
    out[i] = f2bf(src[i & 262143]);
}

// ---------------------------------------------------------------------------
// 2a. GroupNorm stats: grid (4 quarters, 64 b*g); partials -> part[(bg*4+q)*2]
// ---------------------------------------------------------------------------
__global__ __launch_bounds__(256) void gn_stats(
    const float* __restrict__ x, float* __restrict__ part)
{
    const int q = blockIdx.x, bg = blockIdx.y;
    const f4* xv = (const f4*)(x + (size_t)bg * 65536 + q * 16384);
    float s = 0.f, sq = 0.f;
    for (int i = threadIdx.x; i < 4096; i += 256) {
        f4 v = xv[i];
        s  += v.x + v.y + v.z + v.w;
        sq += v.x * v.x + v.y * v.y + v.z * v.z + v.w * v.w;
    }
    #pragma unroll
    for (int off = 32; off > 0; off >>= 1) {
        s  += __shfl_xor(s, off, 64);
        sq += __shfl_xor(sq, off, 64);
    }
    __shared__ float red[8];
    const int w = threadIdx.x >> 6, lane = threadIdx.x & 63;
    if (lane == 0) { red[w] = s; red[4 + w] = sq; }
    __syncthreads();
    if (threadIdx.x == 0) {
        part[(bg * 4 + q) * 2]     = red[0] + red[1] + red[2] + red[3];
        part[(bg * 4 + q) * 2 + 1] = red[4] + red[5] + red[6] + red[7];
    }
}

// ---------------------------------------------------------------------------
// 2b. GroupNorm apply -> h bf16 in [B*N, C] layout.
// ---------------------------------------------------------------------------
__global__ __launch_bounds__(256) void gn_apply(
    const float* __restrict__ x, const float* __restrict__ gamma,
    const float* __restrict__ beta, const float* __restrict__ part,
    unsigned short* __restrict__ h)
{
    const int q = blockIdx.x, bg = blockIdx.y;
    const int b = bg >> 5, g = bg & 31;
    float s = 0.f, sq = 0.f;
    #pragma unroll
    for (int j = 0; j < 4; ++j) {
        s  += part[(bg * 4 + j) * 2];
        sq += part[(bg * 4 + j) * 2 + 1];
    }
    const float mean = s * (1.f / 65536.f);
    const float rstd = rsqrtf(sq * (1.f / 65536.f) - mean * mean + 1e-5f);

    float gm[16], bt[16];
    #pragma unroll
    for (int c = 0; c < 16; ++c) {
        gm[c] = gamma[g * 16 + c] * rstd;
        bt[c] = beta[g * 16 + c];
    }
    const float* xg = x + (size_t)bg * 65536;
    const int n0 = q * 1024 + threadIdx.x * 4;
    float val[16][4];
    #pragma unroll
    for (int c = 0; c < 16; ++c) {
        f4 v = *(const f4*)&xg[(size_t)c * 4096 + n0];
        val[c][0] = (v.x - mean) * gm[c] + bt[c];
        val[c][1] = (v.y - mean) * gm[c] + bt[c];
        val[c][2] = (v.z - mean) * gm[c] + bt[c];
        val[c][3] = (v.w - mean) * gm[c] + bt[c];
    }
    #pragma unroll
    for (int nn = 0; nn < 4; ++nn) {
        ushort8 v0, v1;
        #pragma unroll
        for (int c = 0; c < 8; ++c)  v0[c]     = f2bf(val[c][nn]);
        #pragma unroll
        for (int c = 8; c < 16; ++c) v1[c - 8] = f2bf(val[c][nn]);
        unsigned short* dst = h + ((size_t)(b * 4096 + n0 + nn)) * 512 + g * 16;
        *(ushort8*)dst = v0;
        *(ushort8*)(dst + 8) = v1;
    }
}

// ---------------------------------------------------------------------------
// 3. bf16 GEMM  C[i,j] = sum_k A[i,k]*Bt[j,k] (+bias, +epilogue)
//    MODE 0: fused QKV. cols<1024 (Q,K) -> bf16 [i*N+j] (Q pre-scaled by CS);
//            cols>=1024 (V) -> written ONLY to vt[bh][d][n] (fused transpose).
//    MODE 1: out fp32 transposed to [B,C,H,W] with residual, bias by i.
// ---------------------------------------------------------------------------
template <int MODE>
__global__ __launch_bounds__(256, 2) void gemm_bt(
    const unsigned short* __restrict__ A,   // [M,K] bf16
    const unsigned short* __restrict__ Bt,  // [N,K] bf16
    const float* __restrict__ bias0,
    const float* __restrict__ bias1,
    const float* __restrict__ bias2,
    const float* __restrict__ resid,
    void* __restrict__ outp,
    unsigned short* __restrict__ vtout,
    int M, int N, int K)
{
    __shared__ __attribute__((aligned(16))) unsigned short As[128 * 32];
    __shared__ __attribute__((aligned(16))) unsigned short Bs[128 * 32];
    const int t = threadIdx.x;
    const int w = t >> 6, lane = t & 63;
    const int l15 = lane & 15, l4 = lane >> 4;
    const int bm = blockIdx.y, bn = blockIdx.x;
    const int wm = (w >> 1) * 64, wn = (w & 1) * 64;

    f32x4 acc[4][4] = {};

    const int srow = t >> 2;
    const int sc8  = (t & 3) * 8;

    const unsigned short* gA0 = A  + (size_t)(bm * 128 + srow) * K + sc8;
    const unsigned short* gA1 = gA0 + (size_t)64 * K;
    const unsigned short* gB0 = Bt + (size_t)(bn * 128 + srow) * K + sc8;
    const unsigned short* gB1 = gB0 + (size_t)64 * K;
    unsigned short* lA0 = &As[w * 512];
    unsigned short* lA1 = &As[2048 + w * 512];
    unsigned short* lB0 = &Bs[w * 512];
    unsigned short* lB1 = &Bs[2048 + w * 512];

    for (int k0 = 0; k0 < K; k0 += 32) {
        __syncthreads();
        GLL(gA0 + k0, lA0);
        GLL(gA1 + k0, lA1);
        GLL(gB0 + k0, lB0);
        GLL(gB1 + k0, lB1);
        __syncthreads();

        bf16x8 af[4], bfr[4];
        #pragma unroll
        for (int mt = 0; mt < 4; ++mt)
            af[mt] = *(const bf16x8*)&As[(wm + mt * 16 + l15) * 32 + l4 * 8];
        #pragma unroll
        for (int nt = 0; nt < 4; ++nt)
            bfr[nt] = *(const bf16x8*)&Bs[(wn + nt * 16 + l15) * 32 + l4 * 8];
        #pragma unroll
        for (int mt = 0; mt < 4; ++mt)
            #pragma unroll
            for (int nt = 0; nt < 4; ++nt)
                acc[mt][nt] = __builtin_amdgcn_mfma_f32_16x16x32_bf16(
                    af[mt], bfr[nt], acc[mt][nt], 0, 0, 0);
    }

    if (MODE == 0) {
        unsigned short* outB = (unsigned short*)outp;
        #pragma unroll
        for (int nt = 0; nt < 4; ++nt) {
            int col = bn * 128 + wn + nt * 16 + l15;
            const float* bp = (col < 512) ? bias0 : (col < 1024) ? bias1 : bias2;
            float bv = bp[col & 511];
            if (col < 1024) {                    // Q (pre-scaled) / K -> qkv
                float sc = (col < 512) ? CS : 1.0f;
                #pragma unroll
                for (int mt = 0; mt < 4; ++mt)
                    #pragma unroll
                    for (int r = 0; r < 4; ++r) {
                        int row = bm * 128 + wm + mt * 16 + l4 * 4 + r;
                        outB[(size_t)row * N + col] = f2bf((acc[mt][nt][r] + bv));
                        if (col < 512)
                            outB[(size_t)row * N + col] = f2bf((acc[mt][nt][r] + bv) * CS);
                    }
            } else {                             // V -> vt[bh][d][n] directly
                int hd = col - 1024;             // h*64 + d
                #pragma unroll
                for (int mt = 0; mt < 4; ++mt) {
                    int m = bm * 128 + wm + mt * 16 + l4 * 4;   // n base (r=0)
                    int bb = m >> 12, n = m & 4095;
                    unsigned u0 = pk2bf(acc[mt][nt][0] + bv, acc[mt][nt][1] + bv);
                    unsigned u1 = pk2bf(acc[mt][nt][2] + bv, acc[mt][nt][3] + bv);
                    unsigned short* dst = vtout +
                        ((size_t)(bb * 8 + (hd >> 6)) * 64 + (hd & 63)) * 4096 + n;
                    *(u32x2*)dst = (u32x2){u0, u1};
                }
            }
        }
    } else {
        float* outF = (float*)outp;
        #pragma unroll
        for (int mt = 0; mt < 4; ++mt)
            #pragma unroll
            for (int nt = 0; nt < 4; ++nt)
                #pragma unroll
                for (int r = 0; r < 4; ++r) {
                    int c = bm * 128 + wm + mt * 16 + l4 * 4 + r;
                    int m = bn * 128 + wn + nt * 16 + l15;
                    int b = m >> 12, n = m & 4095;
                    size_t idx = ((size_t)(b * 512 + c)) * 4096 + n;
                    outF[idx] = acc[mt][nt][r] + bias0[c] + resid[idx];
                }
    }
}

// ---------------------------------------------------------------------------
// 4. Flash attention, 32x32x16 MFMA, 64 q/wave, fixed-shift softmax,
//    2-way key split. Block = 4 waves x 64 q = 256 q of one (b,h), half keys.
//    Emits UNNORMALIZED bf16 O-partials + fp32 l-partials; combine_o merges.
// ---------------------------------------------------------------------------
__global__ __launch_bounds__(256, 2) void attn_kernel(
    const unsigned short* __restrict__ qkv, const unsigned short* __restrict__ vt,
    unsigned short* __restrict__ opart, float* __restrict__ lbuf)
{
    __shared__ __attribute__((aligned(16))) unsigned short Ks[64][72];
    __shared__ __attribute__((aligned(16))) unsigned short Vts[64][72];
    __shared__ __attribute__((aligned(16))) unsigned short Oepi[256][72];

    const int bh = blockIdx.y, b = bh >> 3, h = bh & 7;
    const int qbase = blockIdx.x * 256;
    const int s = blockIdx.z, ks0 = s * 2048;
    const int t = threadIdx.x, w = t >> 6, lane = t & 63;
    const int l31 = lane & 31, h5 = lane >> 5;

    const unsigned short* Qg = qkv + ((size_t)(b * 4096 + qbase + w * 64)) * 1536 + h * 64;
    const unsigned short* Kg = qkv + ((size_t)(b * 4096 + ks0)) * 1536 + 512 + h * 64;
    const unsigned short* Vg = vt + ((size_t)bh) * 64 * 4096 + ks0;

    // Q fragments (B-operand, persistent): q=qt*32+l31, d=kc*16+h5*8+j
    bf16x8 qf[2][4];
    #pragma unroll
    for (int qt = 0; qt < 2; ++qt)
        #pragma unroll
        for (int kc = 0; kc < 4; ++kc)
            qf[qt][kc] = *(const bf16x8*)(Qg + (size_t)(qt * 32 + l31) * 1536 + kc * 16 + h5 * 8);

    f32x16 Oacc[2][2] = {};      // [dt][qt], C-layout: col=q, row=d
    float li[2] = {0.f, 0.f};

    // staging: 256 threads x 32 B for each of K (8 KB) and V^T (8 KB)
    const int sr = t >> 2, sc = (t & 3) * 16;
    const unsigned short* gK = Kg + (size_t)sr * 1536 + sc;
    const unsigned short* gV = Vg + (size_t)sr * 4096 + sc;
    unsigned short* lK = &Ks[sr][sc];
    unsigned short* lV = &Vts[sr][sc];

    ushort8 kr[2], vr[2];
    kr[0] = *(const ushort8*)(gK);
    kr[1] = *(const ushort8*)(gK + 8);
    vr[0] = *(const ushort8*)(gV);
    vr[1] = *(const ushort8*)(gV + 8);

    for (int kt = 0; kt < 32; ++kt) {
        __syncthreads();
        *(ushort8*)(lK)     = kr[0];
        *(ushort8*)(lK + 8) = kr[1];
        *(ushort8*)(lV)     = vr[0];
        *(ushort8*)(lV + 8) = vr[1];
        __syncthreads();
        if (kt < 31) {   // prefetch next tile into registers
            const unsigned short* nk = gK + (size_t)(kt + 1) * 64 * 1536;
            const unsigned short* nv = gV + (kt + 1) * 64;
            kr[0] = *(const ushort8*)(nk);
            kr[1] = *(const ushort8*)(nk + 8);
            vr[0] = *(const ushort8*)(nv);
            vr[1] = *(const ushort8*)(nv + 8);
        }

        // ---- S^T tiles: St[qt][ct] = K(ct) @ Q(qt)^T (scale pre-folded) ----
        f32x16 St[2][2] = {};
        #pragma unroll
        for (int ct = 0; ct < 2; ++ct)
            #pragma unroll
            for (int kc = 0; kc < 4; ++kc) {
                bf16x8 kf = *(const bf16x8*)&Ks[ct * 32 + l31][kc * 16 + h5 * 8];
                St[0][ct] = __builtin_amdgcn_mfma_f32_32x32x16_bf16(kf, qf[0][kc], St[0][ct], 0, 0, 0);
                St[1][ct] = __builtin_amdgcn_mfma_f32_32x32x16_bf16(kf, qf[1][kc], St[1][ct], 0, 0, 0);
            }

        // ---- p = exp2(S'); per-lane row sums; pack to PV B-operand ----
        union PU { unsigned u[4]; bf16x8 v; };
        PU pf[2][4];
        #pragma unroll
        for (int qt = 0; qt < 2; ++qt) {
            #pragma unroll
            for (int ct = 0; ct < 2; ++ct)
                #pragma unroll
                for (int r = 0; r < 16; ++r)
                    St[qt][ct][r] = EXP2(St[qt][ct][r]);
            float s0 = 0.f, s1 = 0.f;
            #pragma unroll
            for (int ct = 0; ct < 2; ++ct) {
                s0 += ((St[qt][ct][0] + St[qt][ct][1]) + (St[qt][ct][2] + St[qt][ct][3]))
                    + ((St[qt][ct][4] + St[qt][ct][5]) + (St[qt][ct][6] + St[qt][ct][7]));
                s1 += ((St[qt][ct][8] + St[qt][ct][9]) + (St[qt][ct][10] + St[qt][ct][11]))
                    + ((St[qt][ct][12] + St[qt][ct][13]) + (St[qt][ct][14] + St[qt][ct][15]));
            }
            li[qt] += s0 + s1;

            #pragma unroll
            for (int ct = 0; ct < 2; ++ct) {
                unsigned pk0 = pk2bf(St[qt][ct][0],  St[qt][ct][1]);
                unsigned pk1 = pk2bf(St[qt][ct][2],  St[qt][ct][3]);
                unsigned pk2 = pk2bf(St[qt][ct][4],  St[qt][ct][5]);
                unsigned pk3 = pk2bf(St[qt][ct][6],  St[qt][ct][7]);
                unsigned pk4 = pk2bf(St[qt][ct][8],  St[qt][ct][9]);
                unsigned pk5 = pk2bf(St[qt][ct][10], St[qt][ct][11]);
                unsigned pk6 = pk2bf(St[qt][ct][12], St[qt][ct][13]);
                unsigned pk7 = pk2bf(St[qt][ct][14], St[qt][ct][15]);
                pl32swap(pk0, pk2); pl32swap(pk1, pk3);
                pl32swap(pk4, pk6); pl32swap(pk5, pk7);
                pf[qt][ct * 2].u[0] = pk0; pf[qt][ct * 2].u[1] = pk1;
                pf[qt][ct * 2].u[2] = pk2; pf[qt][ct * 2].u[3] = pk3;
                pf[qt][ct * 2 + 1].u[0] = pk4; pf[qt][ct * 2 + 1].u[1] = pk5;
                pf[qt][ct * 2 + 1].u[2] = pk6; pf[qt][ct * 2 + 1].u[3] = pk7;
            }
        }

        // ---- O^T += V^T(dt) @ P^T(kk) ----
        #pragma unroll
        for (int kk = 0; kk < 4; ++kk)
            #pragma unroll
            for (int dt = 0; dt < 2; ++dt) {
                bf16x8 vf = *(const bf16x8*)&Vts[dt * 32 + l31][kk * 16 + h5 * 8];
                Oacc[dt][0] = __builtin_amdgcn_mfma_f32_32x32x16_bf16(vf, pf[0][kk].v, Oacc[dt][0], 0, 0, 0);
                Oacc[dt][1] = __builtin_amdgcn_mfma_f32_32x32x16_bf16(vf, pf[1][kk].v, Oacc[dt][1], 0, 0, 0);
            }
    }

    // ---- epilogue: UNNORMALIZED partials. l -> lbuf, O -> opart (bf16) ----
    #pragma unroll
    for (int qt = 0; qt < 2; ++qt) {
        float lf = li[qt] + __shfl_xor(li[qt], 32, 64);
        if (h5 == 0)
            lbuf[((size_t)s * 16 + bh) * 4096 + qbase + w * 64 + qt * 32 + l31] = lf;
        #pragma unroll
        for (int dt = 0; dt < 2; ++dt)
            #pragma unroll
            for (int p = 0; p < 8; ++p) {
                int d = dt * 32 + 2 * (p & 1) + 8 * (p >> 1) + 4 * h5;
                unsigned u = pk2bf(Oacc[dt][qt][2 * p], Oacc[dt][qt][2 * p + 1]);
                *(unsigned*)&Oepi[w * 64 + qt * 32 + l31][d] = u;
            }
    }
    // same-wave read-back, 16B stores of [q][64] rows
    unsigned short* Og = opart + (((size_t)s * 16 + bh) * 4096 + qbase + w * 64) * 64;
    #pragma unroll
    for (int c8 = 0; c8 < 8; ++c8) {
        ushort8 val = *(const ushort8*)&Oepi[w * 64 + lane][c8 * 8];
        *(ushort8*)(Og + (size_t)lane * 64 + c8 * 8) = val;
    }
}

// ---------------------------------------------------------------------------
// 5. Combine the two key-split partials: O = (O0+O1)/(l0+l1) -> [B*N, C] bf16
// ---------------------------------------------------------------------------
__global__ __launch_bounds__(256) void combine_o(
    const unsigned short* __restrict__ opart, const float* __restrict__ lbuf,
    unsigned short* __restrict__ o)
{
    int gid = blockIdx.x * 256 + threadIdx.x;   // 524288 = 65536 rows x 8 chunks
    int row = gid >> 3, c8 = gid & 7;           // row = bh*4096 + q
    int bh = row >> 12, q = row & 4095;
    int b = bh >> 3, h = bh & 7;
    float inv = 1.f / (lbuf[row] + lbuf[65536 + row]);
    ushort8 o0 = *(const ushort8*)(opart + (size_t)row * 64 + c8 * 8);
    ushort8 o1 = *(const ushort8*)(opart + (size_t)65536 * 64 + (size_t)row * 64 + c8 * 8);
    ushort8 r;
    #pragma unroll
    for (int i = 0; i < 8; ++i)
        r[i] = f2bf((bf2f(o0[i]) + bf2f(o1[i])) * inv);
    *(ushort8*)(o + ((size_t)(b * 4096 + q)) * 512 + h * 64 + c8 * 8) = r;
}

// ---------------------------------------------------------------------------
// launch
// ---------------------------------------------------------------------------
extern "C" void kernel_launch(void* const* d_in, const int* in_sizes, int n_in,
                              void* d_out, int out_size, void* d_ws, size_t ws_size,
                              hipStream_t stream) {
    const float* x     = (const float*)d_in[0];
    const float* gamma = (const float*)d_in[1];
    const float* beta  = (const float*)d_in[2];
    const float* Wq    = (const float*)d_in[3];
    const float* bq    = (const float*)d_in[4];
    const float* Wk    = (const float*)d_in[5];
    const float* bk    = (const float*)d_in[6];
    const float* Wv    = (const float*)d_in[7];
    const float* bv    = (const float*)d_in[8];
    const float* Wo    = (const float*)d_in[9];
    const float* bo    = (const float*)d_in[10];
    float* out = (float*)d_out;

    char* ws = (char*)d_ws;
    const size_t MB = 1024 * 1024;
    unsigned short* h      = (unsigned short*)(ws);            // 8 MB, reused as O
    unsigned short* qkv    = (unsigned short*)(ws + 8 * MB);   // 24 MB [8192][1536]
    unsigned short* vtb    = (unsigned short*)(ws + 32 * MB);  // 8 MB [bh][64][4096]
    unsigned short* wb     = (unsigned short*)(ws + 40 * MB);  // 2 MB (Wq|Wk|Wv|Wo)
    float*          gnpart = (float*)(ws + 42 * MB);           // 2 KB
    unsigned short* opart  = (unsigned short*)(ws + 43 * MB);  // 16 MB (2 splits)
    float*          lbuf   = (float*)(ws + 59 * MB);           // 512 KB

    convert_w<<<dim3(4096), dim3(256), 0, stream>>>(Wq, Wk, Wv, Wo, wb);
    gn_stats<<<dim3(4, 64), dim3(256), 0, stream>>>(x, gnpart);
    gn_apply<<<dim3(4, 64), dim3(256), 0, stream>>>(x, gamma, beta, gnpart, h);

    // fused qkv = h @ [Wq;Wk;Wv]^T + b; V goes straight to vtb (transposed)
    gemm_bt<0><<<dim3(12, 64), dim3(256), 0, stream>>>(
        h, wb, bq, bk, bv, nullptr, qkv, vtb, 8192, 1536, 512);

    attn_kernel<<<dim3(16, 16, 2), dim3(256), 0, stream>>>(qkv, vtb, opart, lbuf);
    combine_o<<<dim3(2048), dim3(256), 0, stream>>>(opart, lbuf, h);   // O -> h

    // out[b,c,n] = x + (O @ Wo^T + bo)^T : C[c, m] with A=Wo, Bt=O
    gemm_bt<1><<<dim3(64, 4), dim3(256), 0, stream>>>(
        wb + 786432, h, bo, nullptr, nullptr, x, out, nullptr, 512, 8192, 512);
}